// Round 8
// baseline (308.428 us; speedup 1.0000x reference)
//
#include <hip/hip_runtime.h>
#include <stdint.h>

#define NBATCH 8192
#define HID    128
#define DXC    64
#define NN     66
#define NSTEP  20
#define MROWS  16
#define RSTR   136   // rT LDS stride in bf16 elems (272 B rows)
#define DSTR   280   // duL LDS stride in bf16 elems (560 B rows)

typedef __attribute__((ext_vector_type(8))) short short8;
typedef __attribute__((ext_vector_type(4))) float f32x4;

static __device__ __forceinline__ ushort f2bf(float f) {
  union { float f; uint32_t u; } v; v.f = f;
  uint32_t u = v.u;
  u += 0x7fffu + ((u >> 16) & 1u);
  return (ushort)(u >> 16);
}

// ---------------- Threefry2x32 (JAX exact) ----------------
__device__ __forceinline__ void tf2x32(uint32_t k1, uint32_t k2,
                                       uint32_t x0, uint32_t x1,
                                       uint32_t &o0, uint32_t &o1) {
  uint32_t k3 = k1 ^ k2 ^ 0x1BD11BDAu;
  x0 += k1; x1 += k2;
#define RND(r) do { x0 += x1; x1 = (x1 << (r)) | (x1 >> (32 - (r))); x1 ^= x0; } while (0)
  RND(13); RND(15); RND(26); RND(6);
  x0 += k2; x1 += k3 + 1u;
  RND(17); RND(29); RND(16); RND(24);
  x0 += k3; x1 += k1 + 2u;
  RND(13); RND(15); RND(26); RND(6);
  x0 += k1; x1 += k2 + 3u;
  RND(17); RND(29); RND(16); RND(24);
  x0 += k2; x1 += k3 + 4u;
  RND(13); RND(15); RND(26); RND(6);
  x0 += k3; x1 += k1 + 5u;
#undef RND
  o0 = x0; o1 = x1;
}

// ---------------- XLA ErfInv32 (Giles) ----------------
__device__ __forceinline__ float erfinv_f(float x) {
  float w = -log1pf(-x * x);
  float p1, p2;
  {
    float ww = w - 2.5f;
    float p = 2.81022636e-08f;
    p = fmaf(p, ww, 3.43273939e-07f);
    p = fmaf(p, ww, -3.5233877e-06f);
    p = fmaf(p, ww, -4.39150654e-06f);
    p = fmaf(p, ww, 0.00021858087f);
    p = fmaf(p, ww, -0.00125372503f);
    p = fmaf(p, ww, -0.00417768164f);
    p = fmaf(p, ww, 0.246640727f);
    p = fmaf(p, ww, 1.50140941f);
    p1 = p;
  }
  {
    float ww = sqrtf(w) - 3.0f;
    float p = -0.000200214257f;
    p = fmaf(p, ww, 0.000100950558f);
    p = fmaf(p, ww, 0.00134934322f);
    p = fmaf(p, ww, -0.00367342844f);
    p = fmaf(p, ww, 0.00573950773f);
    p = fmaf(p, ww, -0.0076224613f);
    p = fmaf(p, ww, 0.00943887047f);
    p = fmaf(p, ww, 1.00167406f);
    p = fmaf(p, ww, 2.83297682f);
    p2 = p;
  }
  float p = (w < 5.0f) ? p1 : p2;
  return p * x;
}

__device__ __forceinline__ float bits_to_normal(uint32_t bits) {
  float f = __uint_as_float((bits >> 9) | 0x3F800000u) - 1.0f;
  const float LO = -0.99999994f;
  float u = fmaxf(LO, fmaf(f, 2.0f, LO));
  return 1.41421356237f * erfinv_f(u);
}

// ---------------- prep: bake d-scales into bf16 MFMA B-fragments (verified r2) ----------------
// frag layout: [mi(4)][coltile c(8)][ktile kt(4)][lane(64)][j(8)] bf16
//   mi=0: d64*WT1[k][n]   (fwd T)   mi=1: d65*WY1[k][n]   (fwd Y)
//   mi=2: d64*WT1[n][k]   (bwd T)   mi=3: d65*WY1[n][k]   (bwd Y)
__global__ __launch_bounds__(256) void prep_frags(const float* __restrict__ Bp,
                                                  const float* __restrict__ WT1,
                                                  const float* __restrict__ WY1,
                                                  ushort* __restrict__ frag) {
  __shared__ float cb[NN];
  __shared__ float dsc[2];
  int tid = threadIdx.x;
  if (tid < NN) {
    float rs = 0.f;
    for (int j = 0; j < NN; ++j) {
      if (j == tid) continue;
      if (tid == NN - 1 && j < DXC) continue;
      float v = Bp[tid * NN + j];
      rs += 1.f / (1.f + expf(-v));
    }
    cb[tid] = 1.f + rs / 66.f;
  }
  __syncthreads();
  if (tid < 2) {
    int i = 64 + tid;
    float s = 0.f;
    for (int j = 0; j < NN; ++j) {
      if (j == i) continue;
      if (i == NN - 1 && j < DXC) continue;
      float v = Bp[i * NN + j];
      s += (1.f / (1.f + expf(-v))) * cb[j];
    }
    dsc[tid] = cb[i] + s / 66.f;
  }
  __syncthreads();
  float d64 = dsc[0], d65 = dsc[1];

  int g = blockIdx.x * 256 + tid;      // 0..16383
  int lane = g & 63, kt = (g >> 6) & 3, c = (g >> 8) & 7, mi = g >> 11;
  int r16 = lane & 15, q = lane >> 4;
  int bcol = c * 16 + r16;
  const float* W = (mi == 0 || mi == 2) ? WT1 : WY1;
  float d = (mi == 0 || mi == 2) ? d64 : d65;
  bool fwd = (mi < 2);
  ushort v[8];
#pragma unroll
  for (int j = 0; j < 8; ++j) {
    int a = kt * 32 + q * 8 + j;
    float val = fwd ? W[a * HID + bcol] : W[bcol * HID + a];
    v[j] = f2bf(d * val);
  }
  uint4 st;
  st.x = (uint32_t)v[0] | ((uint32_t)v[1] << 16);
  st.y = (uint32_t)v[2] | ((uint32_t)v[3] << 16);
  st.z = (uint32_t)v[4] | ((uint32_t)v[5] << 16);
  st.w = (uint32_t)v[6] | ((uint32_t)v[7] << 16);
  ((uint4*)frag)[g] = st;
}

// ---------------- main: one autonomous wave per 16-row tile, zero cross-wave sync ----------------
__global__ __launch_bounds__(64) void ebm_wave(
    const float* __restrict__ x, const float* __restrict__ t_in,
    const float* __restrict__ W_in, const float* __restrict__ b_in,
    const float* __restrict__ bT1, const float* __restrict__ WT2,
    const float* __restrict__ bY1, const float* __restrict__ WY2,
    const ushort* __restrict__ fragw,
    float* __restrict__ out) {

  __shared__ __align__(16) ushort rT[MROWS * RSTR];
  __shared__ __align__(16) ushort duL[MROWS * DSTR];
  __shared__ __align__(16) float xs[MROWS * DXC];
  __shared__ float nbuf[NSTEP * 2 * MROWS];
  __shared__ uint32_t skeys[NSTEP][2];

  const int tid  = threadIdx.x;     // 0..63, one wave
  const int r16  = tid & 15;
  const int q    = tid >> 4;
  const int brow0 = blockIdx.x * MROWS;

  const short8* fragp = reinterpret_cast<const short8*>(fragw);

  // ---- prologue: keys, x tile ----
  if (tid < NSTEP) {
    uint32_t o0, o1;
    tf2x32(0u, 42u, 0u, (uint32_t)tid, o0, o1);
    skeys[tid][0] = o0; skeys[tid][1] = o1;
  }
  for (int i = tid; i < MROWS * DXC / 4; i += 64)
    ((float4*)xs)[i] = ((const float4*)(x + (size_t)brow0 * DXC))[i];
  __syncthreads();   // 1-wave block: waitcnt only

  // ---- noise for all 16 rows x 20 steps (exact JAX path) ----
  for (int f = tid; f < NSTEP * 2 * MROWS; f += 64) {
    int s = f >> 5, rr = f & 31;
    uint32_t idx = (uint32_t)(2 * (brow0 + (rr >> 1)) + (rr & 1));
    uint32_t o0, o1;
    tf2x32(skeys[s][0], skeys[s][1], 0u, idx, o0, o1);
    nbuf[f] = bits_to_normal(o0 ^ o1);
  }

  // ---- per-lane statics at C-layout: rows q*4+reg, cols 16c+r16 ----
  float wtC[8], wyC[8], bT1C[8], bY1C[8];
  ushort wT2C[8], wY2C[8];
#pragma unroll
  for (int c = 0; c < 8; ++c) {
    int col = 16 * c + r16;
    wtC[c]  = W_in[64 * HID + col];
    wyC[c]  = W_in[65 * HID + col];
    bT1C[c] = bT1[col];
    bY1C[c] = bY1[col];
    wT2C[c] = f2bf(WT2[col]);
    wY2C[c] = f2bf(WY2[col]);
  }

  // ---- static h0 part: h0x[reg][c] for my 4 rows x 8 cols ----
  float h0x[4][8];
#pragma unroll
  for (int c = 0; c < 8; ++c) {
    float bv = b_in[16 * c + r16];
#pragma unroll
    for (int reg = 0; reg < 4; ++reg) h0x[reg][c] = bv;
  }
  for (int cc = 0; cc < DXC; ++cc) {
    float w[8];
#pragma unroll
    for (int c = 0; c < 8; ++c) w[c] = W_in[cc * HID + 16 * c + r16];
#pragma unroll
    for (int reg = 0; reg < 4; ++reg) {
      float xv = xs[(q * 4 + reg) * DXC + cc];
#pragma unroll
      for (int c = 0; c < 8; ++c) h0x[reg][c] = fmaf(xv, w[c], h0x[reg][c]);
    }
  }

  // ---- z state: this lane owns rows q*4+reg (redundant across r16) ----
  float zt[4], zy[4];
#pragma unroll
  for (int reg = 0; reg < 4; ++reg) {
    zt[reg] = t_in[brow0 + q * 4 + reg];
    zy[reg] = 0.f;
  }
  __syncthreads();   // nbuf/xs settled

  for (int s = 0; s < NSTEP; ++s) {
    // ---- A: r = relu(h0 + zt*wt + zy*wy) at C-layout; scatter to rT; mask bits ----
    uint32_t mb = 0;
#pragma unroll
    for (int reg = 0; reg < 4; ++reg) {
#pragma unroll
      for (int c = 0; c < 8; ++c) {
        float h = fmaf(zy[reg], wyC[c], fmaf(zt[reg], wtC[c], h0x[reg][c]));
        ushort rb = f2bf(fmaxf(h, 0.f));
        rT[(q * 4 + reg) * RSTR + 16 * c + r16] = rb;
        mb |= ((short)rb > 0 ? 1u : 0u) << (reg * 8 + c);
      }
    }
    __syncthreads();

    // ---- F: forward u = r@Wd + b -> du into duL (all 8 coltiles, this wave) ----
    {
      short8 ar[4];
#pragma unroll
      for (int kt = 0; kt < 4; ++kt)
        ar[kt] = *reinterpret_cast<const short8*>(&rT[r16 * RSTR + kt * 32 + q * 8]);

#pragma unroll
      for (int c = 0; c < 8; ++c) {
        f32x4 aT = {0.f, 0.f, 0.f, 0.f}, aY = aT;
#pragma unroll
        for (int kt = 0; kt < 4; ++kt) {
          aT = __builtin_amdgcn_mfma_f32_16x16x32_bf16(ar[kt], fragp[((0 * 8 + c) * 4 + kt) * 64 + tid], aT, 0, 0, 0);
          aY = __builtin_amdgcn_mfma_f32_16x16x32_bf16(ar[kt], fragp[((1 * 8 + c) * 4 + kt) * 64 + tid], aY, 0, 0, 0);
        }
#pragma unroll
        for (int reg = 0; reg < 4; ++reg) {
          int rr = q * 4 + reg;
          duL[rr * DSTR + 16 * c + r16]       = (aT[reg] + bT1C[c] > 0.f) ? wT2C[c] : (ushort)0;
          duL[rr * DSTR + 128 + 16 * c + r16] = (aY[reg] + bY1C[c] > 0.f) ? wY2C[c] : (ushort)0;
        }
      }
    }
    __syncthreads();

    // ---- B: backward v = du_T@WdT^T + du_Y@WdY^T; mask; dots; wave reduce ----
    float pt[4] = {0.f, 0.f, 0.f, 0.f}, py[4] = {0.f, 0.f, 0.f, 0.f};
    {
      short8 dT[4], dY[4];
#pragma unroll
      for (int kt = 0; kt < 4; ++kt) {
        dT[kt] = *reinterpret_cast<const short8*>(&duL[r16 * DSTR + kt * 32 + q * 8]);
        dY[kt] = *reinterpret_cast<const short8*>(&duL[r16 * DSTR + 128 + kt * 32 + q * 8]);
      }
#pragma unroll
      for (int c = 0; c < 8; ++c) {
        f32x4 g = {0.f, 0.f, 0.f, 0.f};
#pragma unroll
        for (int kt = 0; kt < 4; ++kt)
          g = __builtin_amdgcn_mfma_f32_16x16x32_bf16(dT[kt], fragp[((2 * 8 + c) * 4 + kt) * 64 + tid], g, 0, 0, 0);
#pragma unroll
        for (int kt = 0; kt < 4; ++kt)
          g = __builtin_amdgcn_mfma_f32_16x16x32_bf16(dY[kt], fragp[((3 * 8 + c) * 4 + kt) * 64 + tid], g, 0, 0, 0);
#pragma unroll
        for (int reg = 0; reg < 4; ++reg) {
          float v = ((mb >> (reg * 8 + c)) & 1u) ? g[reg] : 0.f;
          pt[reg] = fmaf(v, wtC[c], pt[reg]);
          py[reg] = fmaf(v, wyC[c], py[reg]);
        }
      }
    }
#pragma unroll
    for (int reg = 0; reg < 4; ++reg) {
#pragma unroll
      for (int off = 1; off < 16; off <<= 1) {
        pt[reg] += __shfl_xor(pt[reg], off);
        py[reg] += __shfl_xor(py[reg], off);
      }
    }

    // ---- D: z update, fully lane-local (noise precomputed; sums complete) ----
#pragma unroll
    for (int reg = 0; reg < 4; ++reg) {
      int row = q * 4 + reg;
      float nt = nbuf[s * 32 + 2 * row];
      float ny = nbuf[s * 32 + 2 * row + 1];
      zt[reg] = (zt[reg] - 0.005f * pt[reg]) + 0.1f * nt;
      zy[reg] = (zy[reg] - 0.005f * py[reg]) + 0.1f * ny;
    }
    __syncthreads();   // WAR guard on rT/duL before next step (1-wave: cheap)
  }

  if (r16 == 0) {
#pragma unroll
    for (int reg = 0; reg < 4; ++reg)
      out[brow0 + q * 4 + reg] = zy[reg];
  }
}

extern "C" void kernel_launch(void* const* d_in, const int* in_sizes, int n_in,
                              void* d_out, int out_size, void* d_ws, size_t ws_size,
                              hipStream_t stream) {
  const float* x    = (const float*)d_in[0];
  const float* t_in = (const float*)d_in[1];
  const float* Bp   = (const float*)d_in[2];
  const float* W_in = (const float*)d_in[3];
  const float* b_in = (const float*)d_in[4];
  const float* WT1  = (const float*)d_in[5];
  const float* bT1  = (const float*)d_in[6];
  const float* WT2  = (const float*)d_in[7];
  const float* WY1  = (const float*)d_in[9];
  const float* bY1  = (const float*)d_in[10];
  const float* WY2  = (const float*)d_in[11];
  float* out = (float*)d_out;
  ushort* frag = (ushort*)d_ws;   // 128 KiB baked fragments

  prep_frags<<<64, 256, 0, stream>>>(Bp, WT1, WY1, frag);
  ebm_wave<<<NBATCH / MROWS, 64, 0, stream>>>(
      x, t_in, W_in, b_in, bT1, WT2, bY1, WY2, frag, out);
}